// Round 10
// baseline (780.467 us; speedup 1.0000x reference)
//
#include <hip/hip_runtime.h>

#define S_LEN 2048
#define NH 16
#define HD 64
#define NBH 32   // B*H
#define TOPK 256
#define KT 128   // K rows per tile
#define NT 16    // tiles = S_LEN/KT

typedef __bf16 bf16x8_t __attribute__((ext_vector_type(8)));
typedef float  f32x4_t  __attribute__((ext_vector_type(4)));

__device__ __forceinline__ unsigned short rne_bf16(float f) {
    const unsigned x = __float_as_uint(f);
    return (unsigned short)((x + 0x7FFFu + ((x >> 16) & 1u)) >> 16);
}
__device__ __forceinline__ float wredf_add(float v) {
    #pragma unroll
    for (int m = 32; m > 0; m >>= 1) v += __shfl_xor(v, m, 64);
    return v;
}

// ---------------------------------------------------------------------------
// decompose fp32 -> bf16 hi + bf16 lo (RNE both), vectorized x4
// ---------------------------------------------------------------------------
__global__ __launch_bounds__(256)
void decompose_bf16(const float* __restrict__ in, unsigned short* __restrict__ hi,
                    unsigned short* __restrict__ lo, int n4)
{
    const int i = blockIdx.x * 256 + threadIdx.x;
    if (i >= n4) return;
    const float4 v = reinterpret_cast<const float4*>(in)[i];
    const float f[4] = {v.x, v.y, v.z, v.w};
    unsigned short h[4], l[4];
    #pragma unroll
    for (int j = 0; j < 4; ++j) {
        h[j] = rne_bf16(f[j]);
        const float r = f[j] - __uint_as_float((unsigned)h[j] << 16);
        l[j] = rne_bf16(r);
    }
    reinterpret_cast<ushort4*>(hi)[i] = make_ushort4(h[0], h[1], h[2], h[3]);
    reinterpret_cast<ushort4*>(lo)[i] = make_ushort4(l[0], l[1], l[2], l[3]);
}

// ---------------------------------------------------------------------------
// Split-bf16 MFMA GEMM (dense projections) -- unchanged from R9
// ---------------------------------------------------------------------------
__global__ __launch_bounds__(256)
void gemm_mfma_bt(const unsigned short* __restrict__ Ah, const unsigned short* __restrict__ Al,
                  const unsigned short* __restrict__ Bh, const unsigned short* __restrict__ Bl,
                  const float* __restrict__ bias, float* __restrict__ C,
                  unsigned short* __restrict__ Ch, unsigned short* __restrict__ Cl,
                  int M, int N, int K, int mode, int ldc)
{
    __shared__ unsigned short Ash[128][40];
    __shared__ unsigned short Asl[128][40];
    __shared__ unsigned short Bsh[128][40];
    __shared__ unsigned short Bsl[128][40];

    const int tid  = threadIdx.x;
    const int wid  = tid >> 6, lane = tid & 63;
    const int m0   = blockIdx.y * 128, n0 = blockIdx.x * 128;
    const int wr   = (wid >> 1) * 64, wc = (wid & 1) * 64;
    const int r16  = lane & 15, ksub = (lane >> 4) * 8;
    const int srow = tid >> 1;
    const int skb  = (tid & 1) * 16;

    f32x4_t acc[4][4] = {};

    const size_t aBase = (size_t)(m0 + srow) * K + skb;
    const size_t bBase = (size_t)(n0 + srow) * K + skb;

    for (int k0 = 0; k0 < K; k0 += 32) {
        const uint4 a0 = *reinterpret_cast<const uint4*>(&Ah[aBase + k0]);
        const uint4 a1 = *reinterpret_cast<const uint4*>(&Ah[aBase + k0 + 8]);
        const uint4 a2 = *reinterpret_cast<const uint4*>(&Al[aBase + k0]);
        const uint4 a3 = *reinterpret_cast<const uint4*>(&Al[aBase + k0 + 8]);
        const uint4 b0 = *reinterpret_cast<const uint4*>(&Bh[bBase + k0]);
        const uint4 b1 = *reinterpret_cast<const uint4*>(&Bh[bBase + k0 + 8]);
        const uint4 b2 = *reinterpret_cast<const uint4*>(&Bl[bBase + k0]);
        const uint4 b3 = *reinterpret_cast<const uint4*>(&Bl[bBase + k0 + 8]);
        __syncthreads();
        *reinterpret_cast<uint4*>(&Ash[srow][skb])     = a0;
        *reinterpret_cast<uint4*>(&Ash[srow][skb + 8]) = a1;
        *reinterpret_cast<uint4*>(&Asl[srow][skb])     = a2;
        *reinterpret_cast<uint4*>(&Asl[srow][skb + 8]) = a3;
        *reinterpret_cast<uint4*>(&Bsh[srow][skb])     = b0;
        *reinterpret_cast<uint4*>(&Bsh[srow][skb + 8]) = b1;
        *reinterpret_cast<uint4*>(&Bsl[srow][skb])     = b2;
        *reinterpret_cast<uint4*>(&Bsl[srow][skb + 8]) = b3;
        __syncthreads();

        bf16x8_t fah[4], fal[4], fbh[4], fbl[4];
        #pragma unroll
        for (int i = 0; i < 4; ++i) {
            fah[i] = *reinterpret_cast<const bf16x8_t*>(&Ash[wr + i * 16 + r16][ksub]);
            fal[i] = *reinterpret_cast<const bf16x8_t*>(&Asl[wr + i * 16 + r16][ksub]);
        }
        #pragma unroll
        for (int j = 0; j < 4; ++j) {
            fbh[j] = *reinterpret_cast<const bf16x8_t*>(&Bsh[wc + j * 16 + r16][ksub]);
            fbl[j] = *reinterpret_cast<const bf16x8_t*>(&Bsl[wc + j * 16 + r16][ksub]);
        }
        #pragma unroll
        for (int i = 0; i < 4; ++i)
            #pragma unroll
            for (int j = 0; j < 4; ++j) {
                acc[i][j] = __builtin_amdgcn_mfma_f32_16x16x32_bf16(fah[i], fbh[j], acc[i][j], 0, 0, 0);
                acc[i][j] = __builtin_amdgcn_mfma_f32_16x16x32_bf16(fah[i], fbl[j], acc[i][j], 0, 0, 0);
                acc[i][j] = __builtin_amdgcn_mfma_f32_16x16x32_bf16(fal[i], fbh[j], acc[i][j], 0, 0, 0);
            }
    }

    #pragma unroll
    for (int j = 0; j < 4; ++j) {
        const int col = n0 + wc + j * 16 + r16;
        const float bv = bias ? bias[col] : 0.0f;
        #pragma unroll
        for (int i = 0; i < 4; ++i) {
            #pragma unroll
            for (int r = 0; r < 4; ++r) {
                const int row = m0 + wr + i * 16 + (lane >> 4) * 4 + r;
                const float val = acc[i][j][r] + bv;
                if (mode == 0) {
                    C[(size_t)row * ldc + col] = val;
                } else {
                    const int b = row >> 11, s = row & (S_LEN - 1);
                    const int h = col >> 6,  d = col & (HD - 1);
                    const size_t idx = (((size_t)(b * NH + h)) * S_LEN + s) * HD + d;
                    if (mode == 1) {
                        C[idx] = val;
                    } else {
                        const unsigned short hh = rne_bf16(val);
                        Ch[idx] = hh;
                        Cl[idx] = rne_bf16(val - __uint_as_float((unsigned)hh << 16));
                    }
                }
            }
        }
    }
}

// ---------------------------------------------------------------------------
// FUSED: score MFMA + exact top-k(256) + softmax + sparse PV. One kernel,
// scores never touch HBM. 512 threads = 8 waves; block owns 16 Q-rows of one
// head; each wave owns 2 rows (keys in registers, fully unrolled tile loop).
// Score accumulation order identical to R9's gemm_score_mfma -> bit-identical
// selection (absmax must not move).
// ---------------------------------------------------------------------------
#define HCOPY_STRIDE 272
#define HWAVE_WORDS 768

struct LdsA {
    unsigned short qh[16][72], ql[16][72];   // 4.5 KB
    unsigned short kh[KT][72], kl[KT][72];   // 36 KB
    float sb[2][16][132];                    // 16.5 KB double-buffered scores
};
struct LdsB {
    unsigned hist[8][HWAVE_WORDS];           // 24 KB
    unsigned long long ltw[16][TOPK];        // 32 KB
};
union FusedLDS { LdsA a; LdsB b; };

__global__ __launch_bounds__(512, 4)
void fused_score_topk_pv(const unsigned short* __restrict__ Qh, const unsigned short* __restrict__ Ql,
                         const unsigned short* __restrict__ Kh, const unsigned short* __restrict__ Kl,
                         const float* __restrict__ V, float* __restrict__ att)
{
    __shared__ FusedLDS sm;
    const int tid  = threadIdx.x;
    const int w    = tid >> 6, lane = tid & 63;
    const int bh   = blockIdx.y;
    const int rb   = blockIdx.x;
    const size_t headOff = (size_t)bh * S_LEN * HD;

    // ---- stage Q rows (hi/lo) once ----
    if (tid < 256) {
        const int plane = tid >> 7;
        const int t2  = tid & 127;
        const int row = t2 >> 3, col = (t2 & 7) * 8;
        const unsigned short* src = (plane ? Ql : Qh) + headOff + (size_t)(rb * 16 + row) * HD + col;
        const uint4 v = *reinterpret_cast<const uint4*>(src);
        *reinterpret_cast<uint4*>((plane ? sm.a.ql[row] : sm.a.qh[row]) + col) = v;
    }

    unsigned u[2][32];
    unsigned mxu0 = 0u, mxu1 = 0u;

    #pragma unroll
    for (int t = 0; t < NT; ++t) {
        __syncthreads();   // prev MFMA done: K-buf safe; prev-prev sb reads done
        // ---- stage K tile t (hi/lo), linear coalesced ----
        #pragma unroll
        for (int p = 0; p < 2; ++p) {
            const int e   = (p * 512 + tid) * 8;
            const int row = e >> 6, col = e & 63;
            const size_t g = headOff + (size_t)(t * KT + row) * HD + col;
            const uint4 vh = *reinterpret_cast<const uint4*>(&Kh[g]);
            const uint4 vl = *reinterpret_cast<const uint4*>(&Kl[g]);
            *reinterpret_cast<uint4*>(&sm.a.kh[row][col]) = vh;
            *reinterpret_cast<uint4*>(&sm.a.kl[row][col]) = vl;
        }
        __syncthreads();

        // ---- MFMA: 16 rows x cols [w*16, w*16+16), 4-term split, K=64 ----
        f32x4_t acc = {};
        #pragma unroll
        for (int ks = 0; ks < 2; ++ks) {
            const int qrow = lane & 15, ko = (lane >> 4) * 8 + ks * 32;
            const bf16x8_t fqh = *reinterpret_cast<const bf16x8_t*>(&sm.a.qh[qrow][ko]);
            const bf16x8_t fql = *reinterpret_cast<const bf16x8_t*>(&sm.a.ql[qrow][ko]);
            const int krow = w * 16 + (lane & 15);
            const bf16x8_t fkh = *reinterpret_cast<const bf16x8_t*>(&sm.a.kh[krow][ko]);
            const bf16x8_t fkl = *reinterpret_cast<const bf16x8_t*>(&sm.a.kl[krow][ko]);
            acc = __builtin_amdgcn_mfma_f32_16x16x32_bf16(fqh, fkh, acc, 0, 0, 0);
            acc = __builtin_amdgcn_mfma_f32_16x16x32_bf16(fqh, fkl, acc, 0, 0, 0);
            acc = __builtin_amdgcn_mfma_f32_16x16x32_bf16(fql, fkh, acc, 0, 0, 0);
            acc = __builtin_amdgcn_mfma_f32_16x16x32_bf16(fql, fkl, acc, 0, 0, 0);
        }
        #pragma unroll
        for (int r = 0; r < 4; ++r)
            sm.a.sb[t & 1][(lane >> 4) * 4 + r][w * 16 + (lane & 15)] = acc[r] * 0.125f;

        // ---- harvest previous tile's scores into keys (rows 2w, 2w+1) ----
        if (t > 0) {
            #pragma unroll
            for (int j = 0; j < 2; ++j) {
                const int id = (t - 1) * 2 + j;
                {
                    const unsigned b = __float_as_uint(sm.a.sb[(t - 1) & 1][2 * w][j * 64 + lane]);
                    const unsigned k = (b & 0x80000000u) ? ~b : (b | 0x80000000u);
                    u[0][id] = k; mxu0 = k > mxu0 ? k : mxu0;
                }
                {
                    const unsigned b = __float_as_uint(sm.a.sb[(t - 1) & 1][2 * w + 1][j * 64 + lane]);
                    const unsigned k = (b & 0x80000000u) ? ~b : (b | 0x80000000u);
                    u[1][id] = k; mxu1 = k > mxu1 ? k : mxu1;
                }
            }
        }
    }
    __syncthreads();   // last tile's sb writes visible
    #pragma unroll
    for (int j = 0; j < 2; ++j) {
        const int id = (NT - 1) * 2 + j;
        {
            const unsigned b = __float_as_uint(sm.a.sb[(NT - 1) & 1][2 * w][j * 64 + lane]);
            const unsigned k = (b & 0x80000000u) ? ~b : (b | 0x80000000u);
            u[0][id] = k; mxu0 = k > mxu0 ? k : mxu0;
        }
        {
            const unsigned b = __float_as_uint(sm.a.sb[(NT - 1) & 1][2 * w + 1][j * 64 + lane]);
            const unsigned k = (b & 0x80000000u) ? ~b : (b | 0x80000000u);
            u[1][id] = k; mxu1 = k > mxu1 ? k : mxu1;
        }
    }
    __syncthreads();   // all sb reads done before union phase-B overlay

    // ---- per-wave, per-row: exact radix select + softmax + PV ----
    unsigned* const histw = sm.b.hist[w];
    unsigned* const myh   = histw + (lane & 1) * HCOPY_STRIDE;
    const unsigned long long below = (1ull << lane) - 1ull;
    const float* vh = V + headOff;
    const int bb = bh >> 4, hh = bh & 15;

    auto process_row = [&](const unsigned (&ur)[32], unsigned mxu, int lrow) {
        #pragma unroll
        for (int m = 32; m > 0; m >>= 1) {
            const unsigned o = (unsigned)__shfl_xor((int)mxu, m, 64);
            mxu = o > mxu ? o : mxu;
        }
        const float mx = __uint_as_float((mxu & 0x80000000u) ? (mxu & 0x7FFFFFFFu) : ~mxu);

        unsigned prefix = 0;
        int kRem = TOPK;
        unsigned count_eq = 0;

        auto radix_round = [&](int r, bool masked) {
            #pragma unroll
            for (int j = 0; j < 3; ++j)
                *reinterpret_cast<uint4*>(&histw[4 * (lane + 64 * j)]) = make_uint4(0u, 0u, 0u, 0u);
            asm volatile("s_waitcnt lgkmcnt(0)" ::: "memory");
            const int sh = 24 - 8 * r;
            const int ps = 32 - 8 * r;
            #pragma unroll
            for (int i = 0; i < 32; ++i) {
                const unsigned dig = (ur[i] >> sh) & 0xFFu;
                if (!masked) {
                    atomicAdd(&myh[dig], 1u);
                } else {
                    if ((ur[i] >> ps) == prefix) atomicAdd(&myh[dig], 1u);
                }
            }
            asm volatile("s_waitcnt lgkmcnt(0)" ::: "memory");
            const uint4 q0 = *reinterpret_cast<const uint4*>(&histw[0 * HCOPY_STRIDE + 4 * lane]);
            const uint4 q1 = *reinterpret_cast<const uint4*>(&histw[1 * HCOPY_STRIDE + 4 * lane]);
            const unsigned c0 = q0.x + q1.x;
            const unsigned c1 = q0.y + q1.y;
            const unsigned c2 = q0.z + q1.z;
            const unsigned c3 = q0.w + q1.w;
            const unsigned cnt = c0 + c1 + c2 + c3;
            unsigned sfx = cnt;
            #pragma unroll
            for (int dd = 1; dd < 64; dd <<= 1) {
                const unsigned tt = __shfl_down(sfx, dd, 64);
                if (lane + dd < 64) sfx += tt;
            }
            const unsigned g3 = sfx - cnt;
            const unsigned g2 = g3 + c3;
            const unsigned g1 = g2 + c2;
            const unsigned g0 = g1 + c1;
            const unsigned kr = (unsigned)kRem;
            int myd = -1; unsigned mygt = 0, myc = 0;
            if      (g3 < kr && g3 + c3 >= kr) { myd = 4 * lane + 3; mygt = g3; myc = c3; }
            else if (g2 < kr && g2 + c2 >= kr) { myd = 4 * lane + 2; mygt = g2; myc = c2; }
            else if (g1 < kr && g1 + c1 >= kr) { myd = 4 * lane + 1; mygt = g1; myc = c1; }
            else if (g0 < kr && g0 + c0 >= kr) { myd = 4 * lane + 0; mygt = g0; myc = c0; }
            const unsigned long long bal = __ballot(myd >= 0);
            const int src = __ffsll((unsigned long long)bal) - 1;
            const int d   = __shfl(myd, src, 64);
            kRem    -= __shfl((int)mygt, src, 64);
            count_eq = (unsigned)__shfl((int)myc, src, 64);
            prefix = (prefix << 8) | (unsigned)d;
        };

        radix_round(0, false);
        radix_round(1, true);

        unsigned tau;
        bool takeAll;
        if ((unsigned)kRem == count_eq) {
            tau = prefix << 16;
            takeAll = true;
        } else {
            radix_round(2, true);
            radix_round(3, true);
            tau = prefix;
            takeAll = ((unsigned)kRem == count_eq);
        }
        const int quota = kRem;

        unsigned incbits = 0u;
        if (takeAll) {
            #pragma unroll
            for (int i = 0; i < 32; ++i)
                if (ur[i] >= tau) incbits |= (1u << i);
        } else {
            int prev = 0;
            #pragma unroll
            for (int id = 0; id < 32; ++id) {
                const bool tie = (ur[id] == tau);
                const unsigned long long bl = __ballot(tie);
                const int below_cnt = __popcll(bl & below);
                const bool inc = (ur[id] > tau) || (tie && (prev + below_cnt) < quota);
                if (inc) incbits |= (1u << id);
                prev += __popcll(bl);
            }
        }

        // fused exp + denominator + compaction (col = id*64 + lane, ascending)
        float ds = 0.f;
        int base = 0;
        #pragma unroll
        for (int id = 0; id < 32; ++id) {
            const bool inc = ((incbits >> id) & 1u) != 0u;
            const unsigned long long bmask = __ballot(inc);
            float wv = 0.f;
            if (inc) {
                const unsigned uu = ur[id];
                const unsigned bbu = (uu & 0x80000000u) ? (uu & 0x7FFFFFFFu) : ~uu;
                wv = __expf(__uint_as_float(bbu) - mx);
                const int pos = base + __popcll(bmask & below);
                sm.b.ltw[lrow][pos] = ((unsigned long long)__float_as_uint(wv) << 32)
                                    | (unsigned)(id * 64 + lane);
            }
            ds += wv;
            base += __popcll(bmask);
        }
        const float inv = 1.0f / wredf_add(ds);
        asm volatile("s_waitcnt lgkmcnt(0)" ::: "memory");

        float a0 = 0.f, a1 = 0.f, a2 = 0.f, a3 = 0.f;
        for (int idx = 0; idx < TOPK; idx += 4) {
            const unsigned long long e0 = sm.b.ltw[lrow][idx + 0];
            const unsigned long long e1 = sm.b.ltw[lrow][idx + 1];
            const unsigned long long e2 = sm.b.ltw[lrow][idx + 2];
            const unsigned long long e3 = sm.b.ltw[lrow][idx + 3];
            a0 = fmaf(__uint_as_float((unsigned)(e0 >> 32)), vh[(((unsigned)e0) << 6) + lane], a0);
            a1 = fmaf(__uint_as_float((unsigned)(e1 >> 32)), vh[(((unsigned)e1) << 6) + lane], a1);
            a2 = fmaf(__uint_as_float((unsigned)(e2 >> 32)), vh[(((unsigned)e2) << 6) + lane], a2);
            a3 = fmaf(__uint_as_float((unsigned)(e3 >> 32)), vh[(((unsigned)e3) << 6) + lane], a3);
        }

        const int grow = rb * 16 + lrow;
        att[(((size_t)bb * S_LEN + grow) * NH + hh) * HD + lane] = ((a0 + a1) + (a2 + a3)) * inv;
    };

    process_row(u[0], mxu0, 2 * w);
    process_row(u[1], mxu1, 2 * w + 1);
}

// ---------------------------------------------------------------------------
extern "C" void kernel_launch(void* const* d_in, const int* in_sizes, int n_in,
                              void* d_out, int out_size, void* d_ws, size_t ws_size,
                              hipStream_t stream)
{
    const float* x  = (const float*)d_in[0];
    const float* Wq = (const float*)d_in[1];
    const float* bq = (const float*)d_in[2];
    const float* Wk = (const float*)d_in[3];
    const float* bk = (const float*)d_in[4];
    const float* Wv = (const float*)d_in[5];
    const float* bv = (const float*)d_in[6];
    const float* Wo = (const float*)d_in[7];
    const float* bo = (const float*)d_in[8];
    float* out = (float*)d_out;

    const size_t SD       = (size_t)S_LEN * HD;      // 131072
    const size_t qkvElems = (size_t)NBH * SD;        // 4194304
    const size_t wElems   = 1024u * 1024u;

    float* v_ws = (float*)d_ws;                      // 16 MB
    float* attb = v_ws + qkvElems;                   // 16 MB
    unsigned short* xh  = (unsigned short*)(attb + qkvElems);
    unsigned short* xl  = xh + qkvElems;
    unsigned short* wqh = xl + qkvElems;
    unsigned short* wql = wqh + wElems;
    unsigned short* wkh = wql + wElems;
    unsigned short* wkl = wkh + wElems;
    unsigned short* wvh = wkl + wElems;
    unsigned short* wvl = wvh + wElems;
    unsigned short* woh = wvl + wElems;
    unsigned short* wol = woh + wElems;
    unsigned short* qh  = wol + wElems;
    unsigned short* ql  = qh + qkvElems;
    unsigned short* kh  = ql + qkvElems;
    unsigned short* kl  = kh + qkvElems;             // total fixed ~96 MB

    const dim3 blk(256);

    // decompose x + weights into bf16 hi/lo planes
    decompose_bf16<<<dim3(4096), blk, 0, stream>>>(x,  xh,  xl,  (int)(qkvElems / 4));
    decompose_bf16<<<dim3(1024), blk, 0, stream>>>(Wq, wqh, wql, (int)(wElems / 4));
    decompose_bf16<<<dim3(1024), blk, 0, stream>>>(Wk, wkh, wkl, (int)(wElems / 4));
    decompose_bf16<<<dim3(1024), blk, 0, stream>>>(Wv, wvh, wvl, (int)(wElems / 4));
    decompose_bf16<<<dim3(1024), blk, 0, stream>>>(Wo, woh, wol, (int)(wElems / 4));

    // projections: Q,K -> bf16 hi/lo planes (mode 2); V -> fp32 (mode 1)
    gemm_mfma_bt<<<dim3(8, 32), blk, 0, stream>>>(xh, xl, wqh, wql, bq, nullptr, qh, ql, 4096, 1024, 1024, 2, 0);
    gemm_mfma_bt<<<dim3(8, 32), blk, 0, stream>>>(xh, xl, wkh, wkl, bk, nullptr, kh, kl, 4096, 1024, 1024, 2, 0);
    gemm_mfma_bt<<<dim3(8, 32), blk, 0, stream>>>(xh, xl, wvh, wvl, bv, v_ws, nullptr, nullptr, 4096, 1024, 1024, 1, 0);

    // fused QK^T + exact top-k + softmax + PV (no score HBM round-trip)
    fused_score_topk_pv<<<dim3(S_LEN / 16, NBH), dim3(512), 0, stream>>>(qh, ql, kh, kl, v_ws, attb);

    // output projection (reuse x's planes for attb)
    decompose_bf16<<<dim3(4096), blk, 0, stream>>>(attb, xh, xl, (int)(qkvElems / 4));
    gemm_mfma_bt<<<dim3(8, 32), blk, 0, stream>>>(xh, xl, woh, wol, bo, out, nullptr, nullptr, 4096, 1024, 1024, 0, 1024);
}

// Round 12
// 649.914 us; speedup vs baseline: 1.2009x; 1.2009x over previous
//
#include <hip/hip_runtime.h>

#define S_LEN 2048
#define NH 16
#define HD 64
#define NBH 32   // B*H
#define TOPK 256

typedef __bf16 bf16x8_t __attribute__((ext_vector_type(8)));
typedef float  f32x4_t  __attribute__((ext_vector_type(4)));

__device__ __forceinline__ unsigned short rne_bf16(float f) {
    const unsigned x = __float_as_uint(f);
    return (unsigned short)((x + 0x7FFFu + ((x >> 16) & 1u)) >> 16);
}

// ---------------------------------------------------------------------------
// decompose fp32 -> bf16 hi + bf16 lo (RNE both), vectorized x4
// ---------------------------------------------------------------------------
__global__ __launch_bounds__(256)
void decompose_bf16(const float* __restrict__ in, unsigned short* __restrict__ hi,
                    unsigned short* __restrict__ lo, int n4)
{
    const int i = blockIdx.x * 256 + threadIdx.x;
    if (i >= n4) return;
    const float4 v = reinterpret_cast<const float4*>(in)[i];
    const float f[4] = {v.x, v.y, v.z, v.w};
    unsigned short h[4], l[4];
    #pragma unroll
    for (int j = 0; j < 4; ++j) {
        h[j] = rne_bf16(f[j]);
        const float r = f[j] - __uint_as_float((unsigned)h[j] << 16);
        l[j] = rne_bf16(r);
    }
    reinterpret_cast<ushort4*>(hi)[i] = make_ushort4(h[0], h[1], h[2], h[3]);
    reinterpret_cast<ushort4*>(lo)[i] = make_ushort4(l[0], l[1], l[2], l[3]);
}

// ---------------------------------------------------------------------------
// Split-bf16 MFMA GEMM: C = (Ah+Al) @ (Bh+Bl)^T + bias   (3-term, fp32-level)
//   mode 0: C row-major [m][ldc]
//   mode 1: QKV head layout fp32
//   mode 2: QKV head layout, bf16 hi/lo planes (Ch/Cl) -- for Q,K
// ---------------------------------------------------------------------------
__global__ __launch_bounds__(256)
void gemm_mfma_bt(const unsigned short* __restrict__ Ah, const unsigned short* __restrict__ Al,
                  const unsigned short* __restrict__ Bh, const unsigned short* __restrict__ Bl,
                  const float* __restrict__ bias, float* __restrict__ C,
                  unsigned short* __restrict__ Ch, unsigned short* __restrict__ Cl,
                  int M, int N, int K, int mode, int ldc)
{
    __shared__ unsigned short Ash[128][40];
    __shared__ unsigned short Asl[128][40];
    __shared__ unsigned short Bsh[128][40];
    __shared__ unsigned short Bsl[128][40];

    const int tid  = threadIdx.x;
    const int wid  = tid >> 6, lane = tid & 63;
    const int m0   = blockIdx.y * 128, n0 = blockIdx.x * 128;
    const int wr   = (wid >> 1) * 64, wc = (wid & 1) * 64;
    const int r16  = lane & 15, ksub = (lane >> 4) * 8;
    const int srow = tid >> 1;
    const int skb  = (tid & 1) * 16;

    f32x4_t acc[4][4] = {};

    const size_t aBase = (size_t)(m0 + srow) * K + skb;
    const size_t bBase = (size_t)(n0 + srow) * K + skb;

    for (int k0 = 0; k0 < K; k0 += 32) {
        const uint4 a0 = *reinterpret_cast<const uint4*>(&Ah[aBase + k0]);
        const uint4 a1 = *reinterpret_cast<const uint4*>(&Ah[aBase + k0 + 8]);
        const uint4 a2 = *reinterpret_cast<const uint4*>(&Al[aBase + k0]);
        const uint4 a3 = *reinterpret_cast<const uint4*>(&Al[aBase + k0 + 8]);
        const uint4 b0 = *reinterpret_cast<const uint4*>(&Bh[bBase + k0]);
        const uint4 b1 = *reinterpret_cast<const uint4*>(&Bh[bBase + k0 + 8]);
        const uint4 b2 = *reinterpret_cast<const uint4*>(&Bl[bBase + k0]);
        const uint4 b3 = *reinterpret_cast<const uint4*>(&Bl[bBase + k0 + 8]);
        __syncthreads();
        *reinterpret_cast<uint4*>(&Ash[srow][skb])     = a0;
        *reinterpret_cast<uint4*>(&Ash[srow][skb + 8]) = a1;
        *reinterpret_cast<uint4*>(&Asl[srow][skb])     = a2;
        *reinterpret_cast<uint4*>(&Asl[srow][skb + 8]) = a3;
        *reinterpret_cast<uint4*>(&Bsh[srow][skb])     = b0;
        *reinterpret_cast<uint4*>(&Bsh[srow][skb + 8]) = b1;
        *reinterpret_cast<uint4*>(&Bsl[srow][skb])     = b2;
        *reinterpret_cast<uint4*>(&Bsl[srow][skb + 8]) = b3;
        __syncthreads();

        bf16x8_t fah[4], fal[4], fbh[4], fbl[4];
        #pragma unroll
        for (int i = 0; i < 4; ++i) {
            fah[i] = *reinterpret_cast<const bf16x8_t*>(&Ash[wr + i * 16 + r16][ksub]);
            fal[i] = *reinterpret_cast<const bf16x8_t*>(&Asl[wr + i * 16 + r16][ksub]);
        }
        #pragma unroll
        for (int j = 0; j < 4; ++j) {
            fbh[j] = *reinterpret_cast<const bf16x8_t*>(&Bsh[wc + j * 16 + r16][ksub]);
            fbl[j] = *reinterpret_cast<const bf16x8_t*>(&Bsl[wc + j * 16 + r16][ksub]);
        }
        #pragma unroll
        for (int i = 0; i < 4; ++i)
            #pragma unroll
            for (int j = 0; j < 4; ++j) {
                acc[i][j] = __builtin_amdgcn_mfma_f32_16x16x32_bf16(fah[i], fbh[j], acc[i][j], 0, 0, 0);
                acc[i][j] = __builtin_amdgcn_mfma_f32_16x16x32_bf16(fah[i], fbl[j], acc[i][j], 0, 0, 0);
                acc[i][j] = __builtin_amdgcn_mfma_f32_16x16x32_bf16(fal[i], fbh[j], acc[i][j], 0, 0, 0);
            }
    }

    #pragma unroll
    for (int j = 0; j < 4; ++j) {
        const int col = n0 + wc + j * 16 + r16;
        const float bv = bias ? bias[col] : 0.0f;
        #pragma unroll
        for (int i = 0; i < 4; ++i) {
            #pragma unroll
            for (int r = 0; r < 4; ++r) {
                const int row = m0 + wr + i * 16 + (lane >> 4) * 4 + r;
                const float val = acc[i][j][r] + bv;
                if (mode == 0) {
                    C[(size_t)row * ldc + col] = val;
                } else {
                    const int b = row >> 11, s = row & (S_LEN - 1);
                    const int h = col >> 6,  d = col & (HD - 1);
                    const size_t idx = (((size_t)(b * NH + h)) * S_LEN + s) * HD + d;
                    if (mode == 1) {
                        C[idx] = val;
                    } else {
                        const unsigned short hh = rne_bf16(val);
                        Ch[idx] = hh;
                        Cl[idx] = rne_bf16(val - __uint_as_float((unsigned)hh << 16));
                    }
                }
            }
        }
    }
}

// ---------------------------------------------------------------------------
// Score GEMM via 4-term split-bf16 MFMA: S = 0.125 * Q @ K^T  (per head)
// ---------------------------------------------------------------------------
__global__ __launch_bounds__(256)
void gemm_score_mfma(const unsigned short* __restrict__ Qh, const unsigned short* __restrict__ Ql,
                     const unsigned short* __restrict__ Kh, const unsigned short* __restrict__ Kl,
                     float* __restrict__ S)
{
    __shared__ unsigned short pl[4][128 * 64];   // Ah, Al, Bh, Bl

    const int tid  = threadIdx.x;
    const int wid  = tid >> 6, lane = tid & 63;
    const int m0   = blockIdx.y * 128, n0 = blockIdx.x * 128;
    const int wr   = (wid >> 1) * 64, wc = (wid & 1) * 64;
    const int r16  = lane & 15, ko = (lane >> 4) * 8;
    const size_t headOff = (size_t)blockIdx.z * S_LEN * HD;
    S += (size_t)blockIdx.z * S_LEN * S_LEN;

    {
        const int row = tid >> 1, cs = (tid & 1) * 32;
        const size_t gq = headOff + (size_t)(m0 + row) * HD + cs;
        const size_t gk = headOff + (size_t)(n0 + row) * HD + cs;
        const unsigned short* srcs[4] = {Qh + gq, Ql + gq, Kh + gk, Kl + gk};
        #pragma unroll
        for (int p = 0; p < 4; ++p) {
            #pragma unroll
            for (int j = 0; j < 4; ++j) {
                const uint4 v = *reinterpret_cast<const uint4*>(&srcs[p][j * 8]);
                const int idx = (row * 64 + cs + j * 8) ^ ((row & 7) << 3);
                *reinterpret_cast<uint4*>(&pl[p][idx]) = v;
            }
        }
    }
    __syncthreads();

    f32x4_t acc[4][4] = {};
    #pragma unroll
    for (int ks = 0; ks < 2; ++ks) {
        bf16x8_t fah[4], fal[4], fbh[4], fbl[4];
        #pragma unroll
        for (int i = 0; i < 4; ++i) {
            const int row = wr + i * 16 + r16;
            const int idx = (row * 64 + ko + ks * 32) ^ ((row & 7) << 3);
            fah[i] = *reinterpret_cast<const bf16x8_t*>(&pl[0][idx]);
            fal[i] = *reinterpret_cast<const bf16x8_t*>(&pl[1][idx]);
        }
        #pragma unroll
        for (int j = 0; j < 4; ++j) {
            const int row = wc + j * 16 + r16;
            const int idx = (row * 64 + ko + ks * 32) ^ ((row & 7) << 3);
            fbh[j] = *reinterpret_cast<const bf16x8_t*>(&pl[2][idx]);
            fbl[j] = *reinterpret_cast<const bf16x8_t*>(&pl[3][idx]);
        }
        #pragma unroll
        for (int i = 0; i < 4; ++i)
            #pragma unroll
            for (int j = 0; j < 4; ++j) {
                acc[i][j] = __builtin_amdgcn_mfma_f32_16x16x32_bf16(fah[i], fbh[j], acc[i][j], 0, 0, 0);
                acc[i][j] = __builtin_amdgcn_mfma_f32_16x16x32_bf16(fah[i], fbl[j], acc[i][j], 0, 0, 0);
                acc[i][j] = __builtin_amdgcn_mfma_f32_16x16x32_bf16(fal[i], fbh[j], acc[i][j], 0, 0, 0);
                acc[i][j] = __builtin_amdgcn_mfma_f32_16x16x32_bf16(fal[i], fbl[j], acc[i][j], 0, 0, 0);
            }
    }

    #pragma unroll
    for (int j = 0; j < 4; ++j) {
        const int col = n0 + wc + j * 16 + r16;
        #pragma unroll
        for (int i = 0; i < 4; ++i)
            #pragma unroll
            for (int r = 0; r < 4; ++r) {
                const int row = m0 + wr + i * 16 + (lane >> 4) * 4 + r;
                S[(size_t)row * S_LEN + col] = acc[i][j][r] * 0.125f;
            }
    }
}

// ---------------------------------------------------------------------------
// Per-row exact top-k(256) + softmax + sparse PV.
// One wave per row, 4 independent waves/block, 20 KB LDS (8 blocks/CU cap).
// launch_bounds(256,4): VGPR cap 128 (the (256,8) cap of 64 spilled u[32]).
// PV: 8 t-values/iter across 4 lane-groups (float4 V reads, 4x fewer load
// instrs), 2-step shfl_xor cross-group reduce. Selection logic bit-identical
// to R9; only PV summation order differs (fp32-rounding-level).
// ---------------------------------------------------------------------------
__device__ __forceinline__ float wredf_add(float v) {
    #pragma unroll
    for (int m = 32; m > 0; m >>= 1) v += __shfl_xor(v, m, 64);
    return v;
}

#define HCOPY_STRIDE 272   // words; copy1 of bin d sits 16 banks away from copy0
#define HWAVE_WORDS 768    // 2*272 = 544 used, padded for uniform uint4 zeroing

__global__ __launch_bounds__(256, 4)
void topk_softmax_pv(const float* __restrict__ scores, const float* __restrict__ V,
                     float* __restrict__ att, int bh0)
{
    const int wave = threadIdx.x >> 6;
    const int lane = threadIdx.x & 63;
    const int bh   = bh0 + blockIdx.y;
    const int row  = blockIdx.x * 4 + wave;

    const float* srow = scores + (size_t)blockIdx.y * S_LEN * S_LEN + (size_t)row * S_LEN;

    unsigned u[32];
    unsigned mxu = 0u;
    #pragma unroll
    for (int c = 0; c < 8; ++c) {
        const float4 v4 = *reinterpret_cast<const float4*>(&srow[c * 256 + lane * 4]);
        const float f[4] = {v4.x, v4.y, v4.z, v4.w};
        #pragma unroll
        for (int i = 0; i < 4; ++i) {
            const unsigned b = __float_as_uint(f[i]);
            const unsigned k = (b & 0x80000000u) ? ~b : (b | 0x80000000u);
            u[c * 4 + i] = k;
            mxu = k > mxu ? k : mxu;
        }
    }
    #pragma unroll
    for (int m = 32; m > 0; m >>= 1) {
        const unsigned o = (unsigned)__shfl_xor((int)mxu, m, 64);
        mxu = o > mxu ? o : mxu;
    }
    const float mx = __uint_as_float((mxu & 0x80000000u) ? (mxu & 0x7FFFFFFFu) : ~mxu);

    __shared__ unsigned hist[4][HWAVE_WORDS];
    unsigned* const histw = hist[wave];
    unsigned* const myh   = histw + (lane & 1) * HCOPY_STRIDE;

    unsigned prefix = 0;
    int kRem = TOPK;
    unsigned count_eq = 0;

    auto radix_round = [&](int r, bool masked) {
        #pragma unroll
        for (int j = 0; j < 3; ++j)
            *reinterpret_cast<uint4*>(&histw[4 * (lane + 64 * j)]) = make_uint4(0u, 0u, 0u, 0u);
        asm volatile("s_waitcnt lgkmcnt(0)" ::: "memory");
        const int sh = 24 - 8 * r;
        const int ps = 32 - 8 * r;
        #pragma unroll
        for (int i = 0; i < 32; ++i) {
            const unsigned dig = (u[i] >> sh) & 0xFFu;
            if (!masked) {
                atomicAdd(&myh[dig], 1u);
            } else {
                if ((u[i] >> ps) == prefix) atomicAdd(&myh[dig], 1u);
            }
        }
        asm volatile("s_waitcnt lgkmcnt(0)" ::: "memory");
        const uint4 q0 = *reinterpret_cast<const uint4*>(&histw[0 * HCOPY_STRIDE + 4 * lane]);
        const uint4 q1 = *reinterpret_cast<const uint4*>(&histw[1 * HCOPY_STRIDE + 4 * lane]);
        const unsigned c0 = q0.x + q1.x;
        const unsigned c1 = q0.y + q1.y;
        const unsigned c2 = q0.z + q1.z;
        const unsigned c3 = q0.w + q1.w;
        const unsigned cnt = c0 + c1 + c2 + c3;
        unsigned sfx = cnt;
        #pragma unroll
        for (int dd = 1; dd < 64; dd <<= 1) {
            const unsigned t = __shfl_down(sfx, dd, 64);
            if (lane + dd < 64) sfx += t;
        }
        const unsigned g3 = sfx - cnt;
        const unsigned g2 = g3 + c3;
        const unsigned g1 = g2 + c2;
        const unsigned g0 = g1 + c1;
        const unsigned kr = (unsigned)kRem;
        int myd = -1; unsigned mygt = 0, myc = 0;
        if      (g3 < kr && g3 + c3 >= kr) { myd = 4*lane+3; mygt = g3; myc = c3; }
        else if (g2 < kr && g2 + c2 >= kr) { myd = 4*lane+2; mygt = g2; myc = c2; }
        else if (g1 < kr && g1 + c1 >= kr) { myd = 4*lane+1; mygt = g1; myc = c1; }
        else if (g0 < kr && g0 + c0 >= kr) { myd = 4*lane+0; mygt = g0; myc = c0; }
        const unsigned long long bal = __ballot(myd >= 0);
        const int src = __ffsll((unsigned long long)bal) - 1;
        const int d   = __shfl(myd, src, 64);
        kRem    -= __shfl((int)mygt, src, 64);
        count_eq = (unsigned)__shfl((int)myc, src, 64);
        prefix = (prefix << 8) | (unsigned)d;
    };

    radix_round(0, false);
    radix_round(1, true);

    unsigned tau;
    bool takeAll;
    if ((unsigned)kRem == count_eq) {
        tau = prefix << 16;
        takeAll = true;
    } else {
        radix_round(2, true);
        radix_round(3, true);
        tau = prefix;
        takeAll = ((unsigned)kRem == count_eq);
    }
    const int quota = kRem;

    const unsigned long long below = (1ull << lane) - 1ull;
    unsigned incbits = 0u;
    if (takeAll) {
        #pragma unroll
        for (int i = 0; i < 32; ++i)
            if (u[i] >= tau) incbits |= (1u << i);
    } else {
        int prev = 0;
        #pragma unroll
        for (int c = 0; c < 8; ++c) {
            unsigned long long bl[4];
            #pragma unroll
            for (int i = 0; i < 4; ++i) bl[i] = __ballot(u[c * 4 + i] == tau);
            const int below_all = __popcll(bl[0] & below) + __popcll(bl[1] & below)
                                + __popcll(bl[2] & below) + __popcll(bl[3] & below);
            int own = 0;
            #pragma unroll
            for (int i = 0; i < 4; ++i) {
                const bool tie = (u[c * 4 + i] == tau);
                const bool inc = (u[c * 4 + i] > tau) ||
                                 (tie && (prev + below_all + own) < quota);
                own += tie ? 1 : 0;
                if (inc) incbits |= (1u << (c * 4 + i));
            }
            prev += __popcll(bl[0]) + __popcll(bl[1]) + __popcll(bl[2]) + __popcll(bl[3]);
        }
    }

    __shared__ unsigned long long ltw[4][TOPK];
    float ds = 0.f;
    int base = 0;
    #pragma unroll
    for (int c = 0; c < 8; ++c) {
        #pragma unroll
        for (int i = 0; i < 4; ++i) {
            const int id = c * 4 + i;
            const bool inc = ((incbits >> id) & 1u) != 0u;
            const unsigned long long bmask = __ballot(inc);
            float wv = 0.f;
            if (inc) {
                const unsigned uu = u[id];
                const unsigned bb = (uu & 0x80000000u) ? (uu & 0x7FFFFFFFu) : ~uu;
                wv = __expf(__uint_as_float(bb) - mx);
                const int pos = base + __popcll(bmask & below);
                ltw[wave][pos] = ((unsigned long long)__float_as_uint(wv) << 32)
                               | (unsigned)(c * 256 + lane * 4 + i);
            }
            ds += wv;
            base += __popcll(bmask);
        }
    }
    const float inv = 1.0f / wredf_add(ds);
    asm volatile("s_waitcnt lgkmcnt(0)" ::: "memory");

    // ---- PV: 8 t per iter across 4 lane-groups; float4 V reads ----
    const float* vh = V + (size_t)bh * S_LEN * HD;
    const int g  = lane >> 4;          // t-group 0..3
    const int l4 = (lane & 15) * 4;    // d-offset
    f32x4_t acc = {0.f, 0.f, 0.f, 0.f};
    for (int idx = 0; idx < TOPK; idx += 8) {
        const unsigned long long e0 = ltw[wave][idx + g];
        const unsigned long long e1 = ltw[wave][idx + 4 + g];
        const float w0 = __uint_as_float((unsigned)(e0 >> 32));
        const float w1 = __uint_as_float((unsigned)(e1 >> 32));
        const float4 v0 = *reinterpret_cast<const float4*>(&vh[(((unsigned)e0) << 6) + l4]);
        const float4 v1 = *reinterpret_cast<const float4*>(&vh[(((unsigned)e1) << 6) + l4]);
        acc[0] = fmaf(w0, v0.x, acc[0]);
        acc[1] = fmaf(w0, v0.y, acc[1]);
        acc[2] = fmaf(w0, v0.z, acc[2]);
        acc[3] = fmaf(w0, v0.w, acc[3]);
        acc[0] = fmaf(w1, v1.x, acc[0]);
        acc[1] = fmaf(w1, v1.y, acc[1]);
        acc[2] = fmaf(w1, v1.z, acc[2]);
        acc[3] = fmaf(w1, v1.w, acc[3]);
    }
    #pragma unroll
    for (int r = 0; r < 4; ++r) {
        acc[r] += __shfl_xor(acc[r], 16, 64);
        acc[r] += __shfl_xor(acc[r], 32, 64);
    }

    if (lane < 16) {
        const int b = bh >> 4, h = bh & 15;
        float4 o;
        o.x = acc[0] * inv; o.y = acc[1] * inv;
        o.z = acc[2] * inv; o.w = acc[3] * inv;
        *reinterpret_cast<float4*>(&att[(((size_t)b * S_LEN + row) * NH + h) * HD + l4]) = o;
    }
}

// ---------------------------------------------------------------------------
extern "C" void kernel_launch(void* const* d_in, const int* in_sizes, int n_in,
                              void* d_out, int out_size, void* d_ws, size_t ws_size,
                              hipStream_t stream)
{
    const float* x  = (const float*)d_in[0];
    const float* Wq = (const float*)d_in[1];
    const float* bq = (const float*)d_in[2];
    const float* Wk = (const float*)d_in[3];
    const float* bk = (const float*)d_in[4];
    const float* Wv = (const float*)d_in[5];
    const float* bv = (const float*)d_in[6];
    const float* Wo = (const float*)d_in[7];
    const float* bo = (const float*)d_in[8];
    float* out = (float*)d_out;

    const size_t SD       = (size_t)S_LEN * HD;      // 131072
    const size_t qkvElems = (size_t)NBH * SD;        // 4194304
    const size_t wElems   = 1024u * 1024u;

    float* v_ws = (float*)d_ws;                      // 16 MB
    float* attb = v_ws + qkvElems;                   // 16 MB
    unsigned short* xh  = (unsigned short*)(attb + qkvElems);
    unsigned short* xl  = xh + qkvElems;
    unsigned short* wqh = xl + qkvElems;
    unsigned short* wql = wqh + wElems;
    unsigned short* wkh = wql + wElems;
    unsigned short* wkl = wkh + wElems;
    unsigned short* wvh = wkl + wElems;
    unsigned short* wvl = wvh + wElems;
    unsigned short* woh = wvl + wElems;
    unsigned short* wol = woh + wElems;
    unsigned short* qh  = wol + wElems;
    unsigned short* ql  = qh + qkvElems;
    unsigned short* kh  = ql + qkvElems;
    unsigned short* kl  = kh + qkvElems;
    float* sc = (float*)(kl + qkvElems);             // score chunks

    const size_t scorePerHead = (size_t)S_LEN * S_LEN;   // 16 MB
    const size_t fixedBytes = 2 * qkvElems * sizeof(float)
                            + (6 * qkvElems + 8 * wElems) * sizeof(unsigned short);
    size_t availHeads = 0;
    if (ws_size > fixedBytes)
        availHeads = (ws_size - fixedBytes) / (scorePerHead * sizeof(float));
    int hc = (int)(availHeads < 1 ? 1 : (availHeads > (size_t)NBH ? (size_t)NBH : availHeads));
    if (hc > 16) hc = 16;   // 8192-block topk dispatches amortize the tail

    const dim3 blk(256);

    // decompose x + weights into bf16 hi/lo planes
    decompose_bf16<<<dim3(4096), blk, 0, stream>>>(x,  xh,  xl,  (int)(qkvElems / 4));
    decompose_bf16<<<dim3(1024), blk, 0, stream>>>(Wq, wqh, wql, (int)(wElems / 4));
    decompose_bf16<<<dim3(1024), blk, 0, stream>>>(Wk, wkh, wkl, (int)(wElems / 4));
    decompose_bf16<<<dim3(1024), blk, 0, stream>>>(Wv, wvh, wvl, (int)(wElems / 4));
    decompose_bf16<<<dim3(1024), blk, 0, stream>>>(Wo, woh, wol, (int)(wElems / 4));

    // projections: Q,K -> bf16 hi/lo planes (mode 2); V -> fp32 (mode 1)
    gemm_mfma_bt<<<dim3(8, 32), blk, 0, stream>>>(xh, xl, wqh, wql, bq, nullptr, qh, ql, 4096, 1024, 1024, 2, 0);
    gemm_mfma_bt<<<dim3(8, 32), blk, 0, stream>>>(xh, xl, wkh, wkl, bk, nullptr, kh, kl, 4096, 1024, 1024, 2, 0);
    gemm_mfma_bt<<<dim3(8, 32), blk, 0, stream>>>(xh, xl, wvh, wvl, bv, v_ws, nullptr, nullptr, 4096, 1024, 1024, 1, 0);

    // scores (4-term split-bf16 MFMA, fp32 out) + topk/softmax/PV, chunked
    for (int bh0 = 0; bh0 < NBH; bh0 += hc) {
        const int h = (bh0 + hc <= NBH) ? hc : (NBH - bh0);
        gemm_score_mfma<<<dim3(16, 16, h), blk, 0, stream>>>(
            qh + (size_t)bh0 * SD, ql + (size_t)bh0 * SD,
            kh + (size_t)bh0 * SD, kl + (size_t)bh0 * SD, sc);
        topk_softmax_pv<<<dim3(512, h), blk, 0, stream>>>(sc, v_ws, attb, bh0);
    }

    // output projection (reuse x's planes for attb)
    decompose_bf16<<<dim3(4096), blk, 0, stream>>>(attb, xh, xl, (int)(qkvElems / 4));
    gemm_mfma_bt<<<dim3(8, 32), blk, 0, stream>>>(xh, xl, woh, wol, bo, out, nullptr, nullptr, 4096, 1024, 1024, 0, 1024);
}